// Round 2
// baseline (1897.301 us; speedup 1.0000x reference)
//
#include <hip/hip_runtime.h>

// LSTM_8650064134553 : 2-layer stacked LSTM, B=32768, D=128, H=64, 32 steps.
// Round 3: same MFMA hi/lo-split structure as round 2, plus:
//  (a) non-temporal output stores  -> stop the 537MB out-stream from
//      evicting the 360KB weight set out of L2/L3 (FETCH was 2.67GB),
//  (b) fc N-tile repack so each lane owns adjacent output cols -> float2
//      coalesced 128B-contiguous stores (WRITE was 2.1x ideal),
//  (c) step-invariant weight prefetch across barriers (double-buffered in
//      spare VGPRs) -> weight-load latency hidden under epilogues/barriers.

#define B_      32768
#define D_      128
#define H_      64
#define NSTEP_  32
#define ROWS_   64
#define NTHR_   256
#define NBLK_   (B_ / ROWS_)   // 512 blocks -> 2 blocks/CU (64KB LDS each)

typedef __attribute__((ext_vector_type(8))) short  short8v;  // 8 bf16
typedef __attribute__((ext_vector_type(4))) float  float4v;  // mfma acc
typedef __attribute__((ext_vector_type(2))) float  float2v;

// packed-weight offsets in ushort units inside d_ws (total 360448 B)
#define B0H_OFF 0           // 16 ntile * 6 ktile * 64 lane * 8 = 49152
#define B0L_OFF 49152
#define B1H_OFF 98304       // 16 * 4 * 64 * 8 = 32768
#define B1L_OFF 131072
#define BFH_OFF 163840      // 8 * 2 * 64 * 8 = 8192
#define BFL_OFF 172032

// byte offset into an act plane: row-major [64][256] bf16 (512 B rows),
// XOR-swizzled so stride-512 ds_read_b128 columns spread across banks.
#define SWZ(row, bytecol) ((row) * 512 + ((bytecol) ^ (((row) & 7) << 4)))

__device__ __forceinline__ ushort f2bf(float f) {
  uint u = __float_as_uint(f);
  u += 0x7fffu + ((u >> 16) & 1u);      // RNE
  return (ushort)(u >> 16);
}
__device__ __forceinline__ float bf2f(ushort h) {
  return __uint_as_float((uint)h << 16);
}
__device__ __forceinline__ float fsig(float x) {
  float e = __builtin_amdgcn_exp2f(-1.44269504088896f * x);
  return __builtin_amdgcn_rcpf(1.0f + e);
}
__device__ __forceinline__ float ftanh(float x) {
  float e = __builtin_amdgcn_exp2f(2.88539008177793f * x);
  return 1.0f - 2.0f * __builtin_amdgcn_rcpf(e + 1.0f);
}

// Pack weights into MFMA B-fragment order, split into bf16 hi/lo.
// B-fragment (16x16x32): lane l supplies B[k][n] with n = l&15,
// k = (l>>4)*8 + e, e = 0..7.
// Layer N-tile permutation: tile n -> gate q = n&3, cell group g = n>>2,
// original output column = q*64 + g*16 + (l&15).
// fc N-tile permutation: tile n = cg*2+nq -> col = cg*32 + 2*(l&15) + nq
// (lane's two outputs adjacent -> float2 stores in the epilogue).
__global__ void prep_w(const float* __restrict__ Wih0,
                       const float* __restrict__ Whh0,
                       const float* __restrict__ Wih1,
                       const float* __restrict__ Whh1,
                       const float* __restrict__ Wfc,
                       ushort* __restrict__ ws) {
  int idx = blockIdx.x * blockDim.x + threadIdx.x;
  int np  = gridDim.x * blockDim.x;
  // layer 0: K = 192 = [y(128) | h0(64)], 16 N-tiles x 6 k-tiles
  for (int i = idx; i < 16 * 6 * 64 * 8; i += np) {
    int e = i & 7, l = (i >> 3) & 63, r = i >> 9;
    int kt = r % 6, n = r / 6;
    int col = (n & 3) * 64 + (n >> 2) * 16 + (l & 15);
    int k   = kt * 32 + (l >> 4) * 8 + e;
    float v = (k < D_) ? Wih0[col * D_ + k] : Whh0[col * H_ + (k - D_)];
    ushort hi = f2bf(v);
    ws[B0H_OFF + i] = hi;
    ws[B0L_OFF + i] = f2bf(v - bf2f(hi));
  }
  // layer 1: K = 128 = [h0(64) | h1(64)], 16 N-tiles x 4 k-tiles
  for (int i = idx; i < 16 * 4 * 64 * 8; i += np) {
    int e = i & 7, l = (i >> 3) & 63, r = i >> 9;
    int kt = r & 3, n = r >> 2;
    int col = (n & 3) * 64 + (n >> 2) * 16 + (l & 15);
    int k   = kt * 32 + (l >> 4) * 8 + e;
    float v = (k < H_) ? Wih1[col * H_ + k] : Whh1[col * H_ + (k - H_)];
    ushort hi = f2bf(v);
    ws[B1H_OFF + i] = hi;
    ws[B1L_OFF + i] = f2bf(v - bf2f(hi));
  }
  // fc: K = 64 = h1, 8 N-tiles x 2 k-tiles, adjacent-col permutation
  for (int i = idx; i < 8 * 2 * 64 * 8; i += np) {
    int e = i & 7, l = (i >> 3) & 63, r = i >> 9;
    int kt = r & 1, n = r >> 1;
    int col = (n >> 1) * 32 + 2 * (l & 15) + (n & 1);
    int k   = kt * 32 + (l >> 4) * 8 + e;
    float v = Wfc[col * H_ + k];
    ushort hi = f2bf(v);
    ws[BFH_OFF + i] = hi;
    ws[BFL_OFF + i] = f2bf(v - bf2f(hi));
  }
}

// weight-fragment load macros (indices compile-time under full unroll)
#define LOAD_W0(buf, kt_)                                     \
  _Pragma("unroll") for (int q = 0; q < 4; ++q) {             \
    int idx_ = ((cg * 4 + q) * 6 + (kt_)) * 64 + l;           \
    wh[buf][q] = B0h[idx_];  wl[buf][q] = B0l[idx_];          \
  }
#define LOAD_W1(buf, kt_)                                     \
  _Pragma("unroll") for (int q = 0; q < 4; ++q) {             \
    int idx_ = ((cg * 4 + q) * 4 + (kt_)) * 64 + l;           \
    wh[buf][q] = B1h[idx_];  wl[buf][q] = B1l[idx_];          \
  }
#define LOAD_FC(kt_)                                          \
  _Pragma("unroll") for (int nq = 0; nq < 2; ++nq) {          \
    int idx_ = ((cg * 2 + nq) * 2 + (kt_)) * 64 + l;          \
    fh[kt_][nq] = Bfh[idx_];  fl[kt_][nq] = Bfl[idx_];        \
  }
#define LOAD_ACT(base_bytecol)                                \
  _Pragma("unroll") for (int mt = 0; mt < 4; ++mt) {          \
    int row_ = mt * 16 + c16;                                 \
    int off_ = SWZ(row_, (base_bytecol));                     \
    ah[mt] = *(const short8v*)((char*)act_h + off_);          \
    al[mt] = *(const short8v*)((char*)act_l + off_);          \
  }
#define MFMA3(WH, WL)                                         \
  _Pragma("unroll") for (int q = 0; q < 4; ++q)               \
  _Pragma("unroll") for (int mt = 0; mt < 4; ++mt) {          \
    acc[q][mt] = __builtin_amdgcn_mfma_f32_16x16x32_bf16(ah[mt], (WH)[q], acc[q][mt], 0, 0, 0); \
    acc[q][mt] = __builtin_amdgcn_mfma_f32_16x16x32_bf16(al[mt], (WH)[q], acc[q][mt], 0, 0, 0); \
    acc[q][mt] = __builtin_amdgcn_mfma_f32_16x16x32_bf16(ah[mt], (WL)[q], acc[q][mt], 0, 0, 0); \
  }

__global__ __launch_bounds__(NTHR_, 2)
void lstm_fused(const float* __restrict__ x,
                const float* __restrict__ b0,
                const float* __restrict__ b1,
                const float* __restrict__ bfc,
                const ushort* __restrict__ ws,
                float* __restrict__ out) {
  // act layout per row (256 bf16 cols): [ y(0..127) | h0(128..191) | h1(192..255) ]
  __shared__ __align__(16) ushort act_h[ROWS_ * 256];   // 32 KB
  __shared__ __align__(16) ushort act_l[ROWS_ * 256];   // 32 KB

  const int tid  = threadIdx.x;
  const int l    = tid & 63;
  const int cg   = tid >> 6;       // wave id = cell group (16 cells)
  const int c16  = l & 15;
  const int lq   = l >> 4;
  const int row0 = blockIdx.x * ROWS_;

  const short8v* B0h = (const short8v*)(ws + B0H_OFF);
  const short8v* B0l = (const short8v*)(ws + B0L_OFF);
  const short8v* B1h = (const short8v*)(ws + B1H_OFF);
  const short8v* B1l = (const short8v*)(ws + B1L_OFF);
  const short8v* Bfh = (const short8v*)(ws + BFH_OFF);
  const short8v* Bfl = (const short8v*)(ws + BFL_OFF);

  const int ucol = cg * 16 + c16;  // this lane's cell unit 0..63
  const float bi0 = b0[ucol], bf0 = b0[64 + ucol], bg0 = b0[128 + ucol], bo0 = b0[192 + ucol];
  const float bi1 = b1[ucol], bf1 = b1[64 + ucol], bg1 = b1[128 + ucol], bo1 = b1[192 + ucol];
  const int coly0 = cg * 32 + 2 * c16;           // fc output cols (adjacent pair)
  const float by0 = bfc[coly0], by1 = bfc[coly0 + 1];

  float c0s[16], c1s[16];
#pragma unroll
  for (int i = 0; i < 16; ++i) { c0s[i] = 0.f; c1s[i] = 0.f; }

  // init: x -> act cols 0..127 (hi/lo), zero h0/h1 cols
  for (int i = tid; i < ROWS_ * D_; i += NTHR_) {
    int row = i >> 7, col = i & 127;
    float v = x[(size_t)(row0 + row) * D_ + col];
    ushort hh = f2bf(v);
    ushort hl = f2bf(v - bf2f(hh));
    int off = SWZ(row, col * 2);
    *(ushort*)((char*)act_h + off) = hh;
    *(ushort*)((char*)act_l + off) = hl;
  }
  for (int i = tid; i < ROWS_ * 128; i += NTHR_) {
    int row = i >> 7, col = 128 + (i & 127);
    int off = SWZ(row, col * 2);
    *(ushort*)((char*)act_h + off) = 0;
    *(ushort*)((char*)act_l + off) = 0;
  }

  const float4v zf = {0.f, 0.f, 0.f, 0.f};
  short8v wh[2][4], wl[2][4];   // layer0/1 weight double-buffer
  short8v fh[2][2], fl[2][2];   // fc weights [kt][nq]
  short8v ah[4], al[4];         // A fragments

  LOAD_W0(0, 0);                // prime: layer0 kt=0 (step-invariant)
  __syncthreads();

  for (int t = 0; t < NSTEP_; ++t) {
    // ================= layer 0 : gates = [y | h0] @ W0 =================
    float4v acc[4][4];
#pragma unroll
    for (int q = 0; q < 4; ++q)
#pragma unroll
      for (int mt = 0; mt < 4; ++mt) acc[q][mt] = zf;

#pragma unroll
    for (int kt = 0; kt < 6; ++kt) {
      LOAD_ACT((kt * 32 + lq * 8) * 2);
      if (kt < 5) { LOAD_W0((kt + 1) & 1, kt + 1); }   // prefetch next kt
      else        { LOAD_W1(0, 0); }                   // prefetch layer1 kt0
      MFMA3(wh[kt & 1], wl[kt & 1]);
    }
    __syncthreads();   // all waves done reading old h0 region

#pragma unroll
    for (int mt = 0; mt < 4; ++mt)
#pragma unroll
      for (int j = 0; j < 4; ++j) {
        float ig = fsig (acc[0][mt][j] + bi0);
        float fg = fsig (acc[1][mt][j] + bf0);
        float gg = ftanh(acc[2][mt][j] + bg0);
        float og = fsig (acc[3][mt][j] + bo0);
        float cn = fmaf(fg, c0s[mt * 4 + j], ig * gg);
        c0s[mt * 4 + j] = cn;
        float h = og * ftanh(cn);
        ushort hh = f2bf(h);
        ushort hl = f2bf(h - bf2f(hh));
        int row = mt * 16 + lq * 4 + j;
        int off = SWZ(row, (128 + ucol) * 2);
        *(ushort*)((char*)act_h + off) = hh;
        *(ushort*)((char*)act_l + off) = hl;
      }
    __syncthreads();   // new h0 visible

    // ================= layer 1 : gates = [h0 | h1] @ W1 =================
#pragma unroll
    for (int q = 0; q < 4; ++q)
#pragma unroll
      for (int mt = 0; mt < 4; ++mt) acc[q][mt] = zf;

#pragma unroll
    for (int kt = 0; kt < 4; ++kt) {
      LOAD_ACT((128 + kt * 32 + lq * 8) * 2);
      if (kt < 3)  { LOAD_W1((kt + 1) & 1, kt + 1); }  // prefetch next kt
      if (kt == 2) { LOAD_FC(0); }                     // prefetch fc kt0
      if (kt == 3) { LOAD_FC(1); }                     // prefetch fc kt1
      MFMA3(wh[kt & 1], wl[kt & 1]);
    }
    __syncthreads();   // all waves done reading old h1 region

#pragma unroll
    for (int mt = 0; mt < 4; ++mt)
#pragma unroll
      for (int j = 0; j < 4; ++j) {
        float ig = fsig (acc[0][mt][j] + bi1);
        float fg = fsig (acc[1][mt][j] + bf1);
        float gg = ftanh(acc[2][mt][j] + bg1);
        float og = fsig (acc[3][mt][j] + bo1);
        float cn = fmaf(fg, c1s[mt * 4 + j], ig * gg);
        c1s[mt * 4 + j] = cn;
        float h = og * ftanh(cn);
        ushort hh = f2bf(h);
        ushort hl = f2bf(h - bf2f(hh));
        int row = mt * 16 + lq * 4 + j;
        int off = SWZ(row, (192 + ucol) * 2);
        *(ushort*)((char*)act_h + off) = hh;
        *(ushort*)((char*)act_l + off) = hl;
      }
    __syncthreads();   // new h1 visible

    // ================= fc : y = h1 @ Wfc^T + bfc =================
    // reuse acc[0..1][*] as the fc accumulator
#pragma unroll
    for (int nq = 0; nq < 2; ++nq)
#pragma unroll
      for (int mt = 0; mt < 4; ++mt) acc[nq][mt] = zf;

#pragma unroll
    for (int kt = 0; kt < 2; ++kt) {
      LOAD_ACT((192 + kt * 32 + lq * 8) * 2);
      if (kt == 1) { LOAD_W0(0, 0); }                  // prefetch next-step layer0 kt0
#pragma unroll
      for (int nq = 0; nq < 2; ++nq)
#pragma unroll
        for (int mt = 0; mt < 4; ++mt) {
          acc[nq][mt] = __builtin_amdgcn_mfma_f32_16x16x32_bf16(ah[mt], fh[kt][nq], acc[nq][mt], 0, 0, 0);
          acc[nq][mt] = __builtin_amdgcn_mfma_f32_16x16x32_bf16(al[mt], fh[kt][nq], acc[nq][mt], 0, 0, 0);
          acc[nq][mt] = __builtin_amdgcn_mfma_f32_16x16x32_bf16(ah[mt], fl[kt][nq], acc[nq][mt], 0, 0, 0);
        }
    }

    // epilogue: y -> global out (non-temporal, 128B-contiguous float2 rows)
    // and feed back into act cols 0..127 (one packed u32 per plane).
    const size_t obase = (size_t)(t + 1) * (B_ * D_) + (size_t)row0 * D_;
#pragma unroll
    for (int mt = 0; mt < 4; ++mt)
#pragma unroll
      for (int j = 0; j < 4; ++j) {
        int row = mt * 16 + lq * 4 + j;
        float y0v = acc[0][mt][j] + by0;
        float y1v = acc[1][mt][j] + by1;
        float2v yv = {y0v, y1v};
        __builtin_nontemporal_store(yv,
            (float2v*)(out + obase + (size_t)row * D_ + coly0));
        if (t == NSTEP_ - 1) {
          __builtin_nontemporal_store(yv,
              (float2v*)(out + (size_t)(row0 + row) * D_ + coly0));
        }
        ushort h0h = f2bf(y0v);
        ushort h1h = f2bf(y1v);
        uint ph = (uint)h0h | ((uint)h1h << 16);
        uint pl = (uint)f2bf(y0v - bf2f(h0h)) | ((uint)f2bf(y1v - bf2f(h1h)) << 16);
        int off = SWZ(row, coly0 * 2);   // coly0 even -> 4B-aligned, SWZ is 16B-granular
        *(uint*)((char*)act_h + off) = ph;
        *(uint*)((char*)act_l + off) = pl;
      }
    __syncthreads();   // y ready for next step's layer-0 GEMM
  }
}

extern "C" void kernel_launch(void* const* d_in, const int* in_sizes, int n_in,
                              void* d_out, int out_size, void* d_ws, size_t ws_size,
                              hipStream_t stream) {
  const float* x    = (const float*)d_in[0];
  const float* Wih0 = (const float*)d_in[1];
  const float* Whh0 = (const float*)d_in[2];
  const float* b0   = (const float*)d_in[3];
  const float* Wih1 = (const float*)d_in[4];
  const float* Whh1 = (const float*)d_in[5];
  const float* b1   = (const float*)d_in[6];
  const float* Wfc  = (const float*)d_in[7];
  const float* bfc  = (const float*)d_in[8];
  ushort* ws  = (ushort*)d_ws;
  float* out  = (float*)d_out;

  prep_w<<<64, NTHR_, 0, stream>>>(Wih0, Whh0, Wih1, Whh1, Wfc, ws);
  lstm_fused<<<NBLK_, NTHR_, 0, stream>>>(x, b0, b1, bfc, ws, out);
}

// Round 3
// 1278.328 us; speedup vs baseline: 1.4842x; 1.4842x over previous
//
#include <hip/hip_runtime.h>

// LSTM_8650064134553 : 2-layer stacked LSTM, B=32768, D=128, H=64, 32 steps.
// Round 4: fc folded into layer0 (W0' = [Wih0@Wfc ; Whh0], b0' = b0+Wih0@bfc)
//   -> recurrence is [h1|h0] @ W0' (K=128), y never re-enters LDS,
//      act LDS 64KB -> 32KB, MFMA/step -25%, weight stream -18%.
// fc (output-only) computed in phase 2 sharing the h1 A-fragments.
// t-loop forced NOT to unroll (#pragma unroll 1): one ~12KB body that fits
// I-cache for both resident blocks (suspected round-1/2 stall source).
// nt stores reverted (measured harmful); float2 adjacent-col out pack kept.

#define B_      32768
#define D_      128
#define H_      64
#define NSTEP_  32
#define ROWS_   64
#define NTHR_   256
#define NBLK_   (B_ / ROWS_)   // 512 blocks -> 2 blocks/CU

typedef __attribute__((ext_vector_type(8))) short  short8v;  // 8 bf16
typedef __attribute__((ext_vector_type(4))) float  float4v;  // mfma acc
typedef __attribute__((ext_vector_type(2))) float  float2v;

// ws layout (ushort units). Total 425984 B + 1KB fused bias.
#define W0X_H 0        // t=0 layer0 (x-part of Wih0), 16n*4kt*64*8
#define W0X_L 32768
#define W0F_H 65536    // folded layer0: k<64 = Wih0@Wfc, k>=64 = Whh0
#define W0F_L 98304
#define W1_H  131072   // layer1: k<64 = Wih1 (h0), k>=64 = Whh1 (h1)
#define W1_L  163840
#define WF_H  196608   // fc, adjacent-col pack, 8n*2kt*64*8
#define WF_L  204800
#define B0P_BYTE 425984  // float[256] fused layer0 bias

// act planes: [64 rows][128 bf16 cols] = 256 B rows; cols [0..63]=h1,[64..127]=h0
// (at t=0 the 128 cols hold x). XOR swizzle vs stride-256 bank aliasing.
#define SWZ(row, bytecol) ((row) * 256 + ((bytecol) ^ (((row) & 7) << 4)))

__device__ __forceinline__ ushort f2bf(float f) {
  uint u = __float_as_uint(f);
  u += 0x7fffu + ((u >> 16) & 1u);      // RNE
  return (ushort)(u >> 16);
}
__device__ __forceinline__ float bf2f(ushort h) {
  return __uint_as_float((uint)h << 16);
}
__device__ __forceinline__ float fsig(float x) {
  float e = __builtin_amdgcn_exp2f(-1.44269504088896f * x);
  return __builtin_amdgcn_rcpf(1.0f + e);
}
__device__ __forceinline__ float ftanh(float x) {
  float e = __builtin_amdgcn_exp2f(2.88539008177793f * x);
  return 1.0f - 2.0f * __builtin_amdgcn_rcpf(e + 1.0f);
}

// B-fragment (16x16x32): lane l supplies B[k][n], n=l&15, k=(l>>4)*8+e.
// Layer N-tile perm: tile n -> orig col (n&3)*64 + (n>>2)*16 + (l&15).
// fc N-tile perm: tile n -> col (n>>1)*32 + 2*(l&15) + (n&1).
__global__ void prep_w(const float* __restrict__ Wih0,
                       const float* __restrict__ Whh0,
                       const float* __restrict__ b0,
                       const float* __restrict__ Wih1,
                       const float* __restrict__ Whh1,
                       const float* __restrict__ Wfc,
                       const float* __restrict__ bfc,
                       ushort* __restrict__ ws) {
  int idx = blockIdx.x * blockDim.x + threadIdx.x;
  int np  = gridDim.x * blockDim.x;
  // W0X: t=0 layer0, gates = x @ Wih0^T  (K=128 over x)
  for (int i = idx; i < 32768; i += np) {
    int e = i & 7, l = (i >> 3) & 63, r = i >> 9;
    int kt = r & 3, n = r >> 2;
    int col = (n & 3) * 64 + (n >> 2) * 16 + (l & 15);
    int k   = kt * 32 + (l >> 4) * 8 + e;
    float v = Wih0[col * D_ + k];
    ushort hi = f2bf(v);
    ws[W0X_H + i] = hi;
    ws[W0X_L + i] = f2bf(v - bf2f(hi));
  }
  // W0F: folded layer0, input [h1 | h0]
  for (int i = idx; i < 32768; i += np) {
    int e = i & 7, l = (i >> 3) & 63, r = i >> 9;
    int kt = r & 3, n = r >> 2;
    int col = (n & 3) * 64 + (n >> 2) * 16 + (l & 15);
    int k   = kt * 32 + (l >> 4) * 8 + e;
    float v;
    if (k < 64) {               // (Wih0 @ Wfc)[col][k]
      float s = 0.f;
      for (int d = 0; d < D_; ++d)
        s = fmaf(Wih0[col * D_ + d], Wfc[d * H_ + k], s);
      v = s;
    } else {
      v = Whh0[col * H_ + (k - 64)];
    }
    ushort hi = f2bf(v);
    ws[W0F_H + i] = hi;
    ws[W0F_L + i] = f2bf(v - bf2f(hi));
  }
  // W1: layer1, input [h0 | h1]
  for (int i = idx; i < 32768; i += np) {
    int e = i & 7, l = (i >> 3) & 63, r = i >> 9;
    int kt = r & 3, n = r >> 2;
    int col = (n & 3) * 64 + (n >> 2) * 16 + (l & 15);
    int k   = kt * 32 + (l >> 4) * 8 + e;
    float v = (k < 64) ? Wih1[col * H_ + k] : Whh1[col * H_ + (k - 64)];
    ushort hi = f2bf(v);
    ws[W1_H + i] = hi;
    ws[W1_L + i] = f2bf(v - bf2f(hi));
  }
  // WF: fc (output y only), K=64 over h1
  for (int i = idx; i < 8192; i += np) {
    int e = i & 7, l = (i >> 3) & 63, r = i >> 9;
    int kt = r & 1, n = r >> 1;
    int col = (n >> 1) * 32 + 2 * (l & 15) + (n & 1);
    int k   = kt * 32 + (l >> 4) * 8 + e;
    float v = Wfc[col * H_ + k];
    ushort hi = f2bf(v);
    ws[WF_H + i] = hi;
    ws[WF_L + i] = f2bf(v - bf2f(hi));
  }
  // b0p = b0 + Wih0 @ bfc
  float* b0p = (float*)((char*)ws + B0P_BYTE);
  for (int i = idx; i < 256; i += np) {
    float s = b0[i];
    for (int d = 0; d < D_; ++d) s = fmaf(Wih0[i * D_ + d], bfc[d], s);
    b0p[i] = s;
  }
}

#define LOAD_ACT(base_bytecol)                                \
  _Pragma("unroll") for (int mt = 0; mt < 4; ++mt) {          \
    int row_ = mt * 16 + c16;                                 \
    int off_ = SWZ(row_, (base_bytecol));                     \
    ah[mt] = *(const short8v*)((char*)act_h + off_);          \
    al[mt] = *(const short8v*)((char*)act_l + off_);          \
  }

#define MFMA3(BH, BL)                                         \
  _Pragma("unroll") for (int q = 0; q < 4; ++q)               \
  _Pragma("unroll") for (int mt = 0; mt < 4; ++mt) {          \
    acc[q][mt] = __builtin_amdgcn_mfma_f32_16x16x32_bf16(ah[mt], (BH)[q], acc[q][mt], 0, 0, 0); \
    acc[q][mt] = __builtin_amdgcn_mfma_f32_16x16x32_bf16(al[mt], (BH)[q], acc[q][mt], 0, 0, 0); \
    acc[q][mt] = __builtin_amdgcn_mfma_f32_16x16x32_bf16(ah[mt], (BL)[q], acc[q][mt], 0, 0, 0); \
  }

// phase-1 GEMM: reads act cols 0..127 with weight plane (BH,BL), K=128
#define GEMM_P1(BH, BL)                                       \
  _Pragma("unroll") for (int kt = 0; kt < 4; ++kt) {          \
    LOAD_ACT((kt * 32 + lq * 8) * 2);                         \
    short8v bh[4], bl[4];                                     \
    _Pragma("unroll") for (int q = 0; q < 4; ++q) {           \
      int idx_ = ((cg * 4 + q) * 4 + kt) * 64 + l;            \
      bh[q] = (BH)[idx_];  bl[q] = (BL)[idx_];                \
    }                                                         \
    MFMA3(bh, bl);                                            \
  }

__device__ __forceinline__ void lstm_ep(float4v (&acc)[4][4], float (&cs)[16],
                                        ushort* act_h, ushort* act_l,
                                        int colbase, int ucol, int lq,
                                        float bi, float bf, float bg, float bo) {
#pragma unroll
  for (int mt = 0; mt < 4; ++mt)
#pragma unroll
    for (int j = 0; j < 4; ++j) {
      float ig = fsig (acc[0][mt][j] + bi);
      float fg = fsig (acc[1][mt][j] + bf);
      float gg = ftanh(acc[2][mt][j] + bg);
      float og = fsig (acc[3][mt][j] + bo);
      float cn = fmaf(fg, cs[mt * 4 + j], ig * gg);
      cs[mt * 4 + j] = cn;
      float h = og * ftanh(cn);
      ushort hh = f2bf(h);
      ushort hl = f2bf(h - bf2f(hh));
      int row = mt * 16 + lq * 4 + j;
      int off = SWZ(row, (colbase + ucol) * 2);
      *(ushort*)((char*)act_h + off) = hh;
      *(ushort*)((char*)act_l + off) = hl;
    }
}

__global__ __launch_bounds__(NTHR_, 2)
void lstm_fused(const float* __restrict__ x,
                const float* __restrict__ b0,
                const float* __restrict__ b1,
                const float* __restrict__ bfc,
                const ushort* __restrict__ ws,
                float* __restrict__ out) {
  __shared__ __align__(16) ushort s_act_h[ROWS_ * 128];   // 16 KB
  __shared__ __align__(16) ushort s_act_l[ROWS_ * 128];   // 16 KB (total 32 KB)
  ushort* act_h = &s_act_h[0];
  ushort* act_l = &s_act_l[0];

  const int tid  = threadIdx.x;
  const int l    = tid & 63;
  const int cg   = tid >> 6;       // wave id = cell group (16 cells)
  const int c16  = l & 15;
  const int lq   = l >> 4;
  const int row0 = blockIdx.x * ROWS_;

  const short8v* W0Xh = (const short8v*)(ws + W0X_H);
  const short8v* W0Xl = (const short8v*)(ws + W0X_L);
  const short8v* W0Fh = (const short8v*)(ws + W0F_H);
  const short8v* W0Fl = (const short8v*)(ws + W0F_L);
  const short8v* W1h  = (const short8v*)(ws + W1_H);
  const short8v* W1l  = (const short8v*)(ws + W1_L);
  const short8v* WFh  = (const short8v*)(ws + WF_H);
  const short8v* WFl  = (const short8v*)(ws + WF_L);
  const float*   b0p  = (const float*)((const char*)ws + B0P_BYTE);

  const int ucol = cg * 16 + c16;  // this lane's cell 0..63
  // t=0 layer0 biases (original b0); folded biases for t>=1
  const float bi0x = b0[ucol],  bf0x = b0[64 + ucol],  bg0x = b0[128 + ucol],  bo0x = b0[192 + ucol];
  const float bi0f = b0p[ucol], bf0f = b0p[64 + ucol], bg0f = b0p[128 + ucol], bo0f = b0p[192 + ucol];
  const float bi1 = b1[ucol], bf1 = b1[64 + ucol], bg1 = b1[128 + ucol], bo1 = b1[192 + ucol];
  const int coly0 = cg * 32 + 2 * c16;     // fc output cols (adjacent pair)
  const float by0 = bfc[coly0], by1 = bfc[coly0 + 1];

  float c0s[16], c1s[16];
#pragma unroll
  for (int i = 0; i < 16; ++i) { c0s[i] = 0.f; c1s[i] = 0.f; }

  // init: x (hi/lo) -> act cols 0..127
  for (int i = tid; i < ROWS_ * D_; i += NTHR_) {
    int row = i >> 7, col = i & 127;
    float v = x[(size_t)(row0 + row) * D_ + col];
    ushort hh = f2bf(v);
    ushort hl = f2bf(v - bf2f(hh));
    int off = SWZ(row, col * 2);
    *(ushort*)((char*)act_h + off) = hh;
    *(ushort*)((char*)act_l + off) = hl;
  }
  __syncthreads();

  const float4v zf = {0.f, 0.f, 0.f, 0.f};
  short8v ah[4], al[4];
  float4v acc[4][4];

  // ===================== t = 0 (input = x) =====================
  {
#pragma unroll
    for (int q = 0; q < 4; ++q)
#pragma unroll
      for (int mt = 0; mt < 4; ++mt) acc[q][mt] = zf;
    GEMM_P1(W0Xh, W0Xl);               // gates0 = x @ Wih0^T (h0=0)
    __syncthreads();
    lstm_ep(acc, c0s, act_h, act_l, 64, ucol, lq, bi0x, bf0x, bg0x, bo0x);
    __syncthreads();

    // layer1 t0: gates = h0 @ Wih1^T only (h1=0): kt 0..1 (act cols 64..127)
#pragma unroll
    for (int q = 0; q < 4; ++q)
#pragma unroll
      for (int mt = 0; mt < 4; ++mt) acc[q][mt] = zf;
#pragma unroll
    for (int kt = 0; kt < 2; ++kt) {
      LOAD_ACT((64 + kt * 32 + lq * 8) * 2);
      short8v bh[4], bl[4];
#pragma unroll
      for (int q = 0; q < 4; ++q) {
        int idx_ = ((cg * 4 + q) * 4 + kt) * 64 + l;
        bh[q] = W1h[idx_];  bl[q] = W1l[idx_];
      }
      MFMA3(bh, bl);
    }
    __syncthreads();
    lstm_ep(acc, c1s, act_h, act_l, 0, ucol, lq, bi1, bf1, bg1, bo1);
    __syncthreads();
  }

  // ===================== t = 1 .. 31 (uniform, NOT unrolled) =====================
#pragma unroll 1
  for (int t = 1; t < NSTEP_; ++t) {
    // P1: gates0 = [h1 | h0] @ W0'  (folded; cols 0..127)
#pragma unroll
    for (int q = 0; q < 4; ++q)
#pragma unroll
      for (int mt = 0; mt < 4; ++mt) acc[q][mt] = zf;
    GEMM_P1(W0Fh, W0Fl);
    __syncthreads();
    lstm_ep(acc, c0s, act_h, act_l, 64, ucol, lq, bi0f, bf0f, bg0f, bo0f);
    __syncthreads();

    // P2: gates1 = [h0 | h1] @ W1 ; fc y_{t-1} on the h1 k-tiles (kt>=2)
    float4v af[2][4];
#pragma unroll
    for (int q = 0; q < 4; ++q)
#pragma unroll
      for (int mt = 0; mt < 4; ++mt) acc[q][mt] = zf;
#pragma unroll
    for (int nq = 0; nq < 2; ++nq)
#pragma unroll
      for (int mt = 0; mt < 4; ++mt) af[nq][mt] = zf;

#pragma unroll
    for (int kt = 0; kt < 4; ++kt) {
      const int cb = (kt < 2) ? (64 + kt * 32) : ((kt - 2) * 32);
      LOAD_ACT((cb + lq * 8) * 2);
      short8v bh[4], bl[4];
#pragma unroll
      for (int q = 0; q < 4; ++q) {
        int idx_ = ((cg * 4 + q) * 4 + kt) * 64 + l;
        bh[q] = W1h[idx_];  bl[q] = W1l[idx_];
      }
      MFMA3(bh, bl);
      if (kt >= 2) {                      // same A frags = h1_{t-1}
        const int ktf = kt - 2;
        short8v fbh[2], fbl[2];
#pragma unroll
        for (int nq = 0; nq < 2; ++nq) {
          int idx_ = ((cg * 2 + nq) * 2 + ktf) * 64 + l;
          fbh[nq] = WFh[idx_];  fbl[nq] = WFl[idx_];
        }
#pragma unroll
        for (int nq = 0; nq < 2; ++nq)
#pragma unroll
          for (int mt = 0; mt < 4; ++mt) {
            af[nq][mt] = __builtin_amdgcn_mfma_f32_16x16x32_bf16(ah[mt], fbh[nq], af[nq][mt], 0, 0, 0);
            af[nq][mt] = __builtin_amdgcn_mfma_f32_16x16x32_bf16(al[mt], fbh[nq], af[nq][mt], 0, 0, 0);
            af[nq][mt] = __builtin_amdgcn_mfma_f32_16x16x32_bf16(ah[mt], fbl[nq], af[nq][mt], 0, 0, 0);
          }
      }
    }
    __syncthreads();
    lstm_ep(acc, c1s, act_h, act_l, 0, ucol, lq, bi1, bf1, bg1, bo1);

    // y_{t-1} -> out row t  (128B-contiguous float2 per wave-row)
    const size_t obase = (size_t)t * (B_ * D_) + (size_t)row0 * D_;
#pragma unroll
    for (int mt = 0; mt < 4; ++mt)
#pragma unroll
      for (int j = 0; j < 4; ++j) {
        int row = mt * 16 + lq * 4 + j;
        float2v yv = {af[0][mt][j] + by0, af[1][mt][j] + by1};
        *(float2v*)(out + obase + (size_t)row * D_ + coly0) = yv;
      }
    __syncthreads();
  }

  // ===================== tail: y_31 from h1_31 =====================
  {
    float4v af[2][4];
#pragma unroll
    for (int nq = 0; nq < 2; ++nq)
#pragma unroll
      for (int mt = 0; mt < 4; ++mt) af[nq][mt] = zf;
#pragma unroll
    for (int ktf = 0; ktf < 2; ++ktf) {
      LOAD_ACT((ktf * 32 + lq * 8) * 2);
      short8v fbh[2], fbl[2];
#pragma unroll
      for (int nq = 0; nq < 2; ++nq) {
        int idx_ = ((cg * 2 + nq) * 2 + ktf) * 64 + l;
        fbh[nq] = WFh[idx_];  fbl[nq] = WFl[idx_];
      }
#pragma unroll
      for (int nq = 0; nq < 2; ++nq)
#pragma unroll
        for (int mt = 0; mt < 4; ++mt) {
          af[nq][mt] = __builtin_amdgcn_mfma_f32_16x16x32_bf16(ah[mt], fbh[nq], af[nq][mt], 0, 0, 0);
          af[nq][mt] = __builtin_amdgcn_mfma_f32_16x16x32_bf16(al[mt], fbh[nq], af[nq][mt], 0, 0, 0);
          af[nq][mt] = __builtin_amdgcn_mfma_f32_16x16x32_bf16(ah[mt], fbl[nq], af[nq][mt], 0, 0, 0);
        }
    }
    const size_t ob32 = (size_t)NSTEP_ * (B_ * D_) + (size_t)row0 * D_;
#pragma unroll
    for (int mt = 0; mt < 4; ++mt)
#pragma unroll
      for (int j = 0; j < 4; ++j) {
        int row = mt * 16 + lq * 4 + j;
        float2v yv = {af[0][mt][j] + by0, af[1][mt][j] + by1};
        *(float2v*)(out + ob32 + (size_t)row * D_ + coly0) = yv;                 // y_stack[31]
        *(float2v*)(out + (size_t)(row0 + row) * D_ + coly0) = yv;               // y_last
      }
  }
}

extern "C" void kernel_launch(void* const* d_in, const int* in_sizes, int n_in,
                              void* d_out, int out_size, void* d_ws, size_t ws_size,
                              hipStream_t stream) {
  const float* x    = (const float*)d_in[0];
  const float* Wih0 = (const float*)d_in[1];
  const float* Whh0 = (const float*)d_in[2];
  const float* b0   = (const float*)d_in[3];
  const float* Wih1 = (const float*)d_in[4];
  const float* Whh1 = (const float*)d_in[5];
  const float* b1   = (const float*)d_in[6];
  const float* Wfc  = (const float*)d_in[7];
  const float* bfc  = (const float*)d_in[8];
  ushort* ws  = (ushort*)d_ws;
  float* out  = (float*)d_out;

  prep_w<<<64, NTHR_, 0, stream>>>(Wih0, Whh0, b0, Wih1, Whh1, Wfc, bfc, ws);
  lstm_fused<<<NBLK_, NTHR_, 0, stream>>>(x, b0, b1, bfc, ws, out);
}